// Round 1
// baseline (288.164 us; speedup 1.0000x reference)
//
#include <hip/hip_runtime.h>
#include <hip/hip_bf16.h>

// out[m][n] = sum_k x[m][k] * W[n][k] + b[n]
// M=1024, N=32768, K=512, fp32 in/out.
// Single-phase fused kernel: fp32 tiles are reg-staged, converted to bf16
// in-register, written to XOR-swizzled double-buffered LDS (one barrier per
// K-step), MFMA 16x16x32 bf16. No workspace, no separate convert pass.

typedef __bf16 bf16x8 __attribute__((ext_vector_type(8)));
typedef float  f32x4  __attribute__((ext_vector_type(4)));

#define MM 1024
#define NN 32768
#define KD 512
#define BM 128
#define BN 128
#define BK 64
#define NKT (KD / BK)   // 8

// 16B-chunk swizzle within a 64-bf16 (128 B) row: conflict-free on both
// ds_write_b128 (lanes l,l+16,l+32,l+48 share (row&7) but differ in row>>3)
// and ds_read_b128 (16 lanes spread over 8 chunk slots, 2-way = free).
__device__ __forceinline__ int swz(int row, int ch) {
    return ch ^ (row & 7) ^ ((row >> 3) & 3);
}

__global__ __launch_bounds__(256, 2)
void gemm_fused_bias(const float* __restrict__ X, const float* __restrict__ W,
                     const float* __restrict__ Bv, float* __restrict__ Out)
{
    __shared__ __bf16 As[2][BM * BK];   // 2 x 16 KB
    __shared__ __bf16 Bs[2][BN * BK];   // 2 x 16 KB

    const int tid  = threadIdx.x;
    const int lane = tid & 63;
    const int ln15 = lane & 15;
    const int quad = lane >> 4;
    const int wave = tid >> 6;
    const int wr   = wave >> 1;
    const int wc   = wave & 1;

    // XCD swizzle: 8 consecutive same-XCD blocks share one W tile (L2 reuse).
    const int blk = (int)blockIdx.x;
    const int xcd = blk & 7;
    const int bm  = (blk >> 3) & 7;          // M/128 = 8
    const int bn  = xcd * 32 + (blk >> 6);   // N/128 = 256

    // staging: thread t owns row t>>1, fp32 cols (t&1)*32 .. +31 of each tile
    const int srow  = tid >> 1;
    const int shalf = tid & 1;
    const float* Ag = X + (size_t)(bm * BM + srow) * KD + shalf * 32;
    const float* Bg = W + (size_t)(bn * BN + srow) * KD + shalf * 32;

    f32x4 acc[4][4];
#pragma unroll
    for (int i = 0; i < 4; ++i)
#pragma unroll
        for (int j = 0; j < 4; ++j)
            acc[i][j] = (f32x4){0.f, 0.f, 0.f, 0.f};

    // prologue: load K-step 0 into regs (16 x dwordx4)
    f32x4 av[8], bv[8];
#pragma unroll
    for (int c = 0; c < 4; ++c) {
        av[2*c]   = *(const f32x4*)(Ag + c * 8);
        av[2*c+1] = *(const f32x4*)(Ag + c * 8 + 4);
        bv[2*c]   = *(const f32x4*)(Bg + c * 8);
        bv[2*c+1] = *(const f32x4*)(Bg + c * 8 + 4);
    }

    const int n0 = bn * BN + wc * 64 + ln15;
    float bias[4];
#pragma unroll
    for (int j = 0; j < 4; ++j) bias[j] = Bv[n0 + j * 16];

#pragma unroll 2
    for (int kt = 0; kt < NKT; ++kt) {
        // --- convert current regs -> bf16, swizzled LDS write (buf kt&1) ---
        __bf16* Aw = As[kt & 1] + srow * BK;
        __bf16* Bw = Bs[kt & 1] + srow * BK;
#pragma unroll
        for (int c = 0; c < 4; ++c) {
            const int ch = shalf * 4 + c;
            bf16x8 oa, ob;
#pragma unroll
            for (int e = 0; e < 4; ++e) {
                oa[e]     = (__bf16)av[2*c][e];
                oa[e + 4] = (__bf16)av[2*c + 1][e];
                ob[e]     = (__bf16)bv[2*c][e];
                ob[e + 4] = (__bf16)bv[2*c + 1][e];
            }
            *(bf16x8*)(Aw + swz(srow, ch) * 8) = oa;
            *(bf16x8*)(Bw + swz(srow, ch) * 8) = ob;
        }

        // --- async-split: issue next K-step's loads; retire under MFMA ---
        if (kt + 1 < NKT) {
            const int ko = (kt + 1) * BK;
#pragma unroll
            for (int c = 0; c < 4; ++c) {
                av[2*c]   = *(const f32x4*)(Ag + ko + c * 8);
                av[2*c+1] = *(const f32x4*)(Ag + ko + c * 8 + 4);
                bv[2*c]   = *(const f32x4*)(Bg + ko + c * 8);
                bv[2*c+1] = *(const f32x4*)(Bg + ko + c * 8 + 4);
            }
        }

        // single barrier per K-step: publishes buf[kt&1]; the other buffer is
        // only rewritten two iterations later, after the next barrier.
        __syncthreads();

        // --- ds_read fragments + MFMA on buf[kt&1] ---
        const __bf16* Ar = As[kt & 1];
        const __bf16* Br = Bs[kt & 1];
#pragma unroll
        for (int kk = 0; kk < 2; ++kk) {
            bf16x8 af[4], bfr[4];
#pragma unroll
            for (int i = 0; i < 4; ++i) {
                const int ar = wr * 64 + i * 16 + ln15;
                af[i] = *(const bf16x8*)(Ar + ar * BK + swz(ar, kk * 4 + quad) * 8);
            }
#pragma unroll
            for (int j = 0; j < 4; ++j) {
                const int br = wc * 64 + j * 16 + ln15;
                bfr[j] = *(const bf16x8*)(Br + br * BK + swz(br, kk * 4 + quad) * 8);
            }
#pragma unroll
            for (int i = 0; i < 4; ++i)
#pragma unroll
                for (int j = 0; j < 4; ++j)
                    acc[i][j] = __builtin_amdgcn_mfma_f32_16x16x32_bf16(
                        af[i], bfr[j], acc[i][j], 0, 0, 0);
        }
    }

    // epilogue: C/D layout col=lane&15, row=quad*4+reg (verified prior session)
    const int m0 = bm * BM + wr * 64 + quad * 4;
#pragma unroll
    for (int i = 0; i < 4; ++i) {
#pragma unroll
        for (int r = 0; r < 4; ++r) {
            float* o = Out + (size_t)(m0 + i * 16 + r) * NN + n0;
#pragma unroll
            for (int j = 0; j < 4; ++j)
                o[j * 16] = acc[i][j][r] + bias[j];
        }
    }
}

extern "C" void kernel_launch(void* const* d_in, const int* in_sizes, int n_in,
                              void* d_out, int out_size, void* d_ws, size_t ws_size,
                              hipStream_t stream) {
    const float* x = (const float*)d_in[0];
    const float* W = (const float*)d_in[1];
    const float* b = (const float*)d_in[2];
    (void)d_ws; (void)ws_size; (void)in_sizes; (void)n_in; (void)out_size;
    const int grid = (MM / BM) * (NN / BN);   // 2048
    gemm_fused_bias<<<dim3(grid), dim3(256), 0, stream>>>(x, W, b, (float*)d_out);
}